// Round 1
// baseline (1647.497 us; speedup 1.0000x reference)
//
#include <hip/hip_runtime.h>

#define NN 100000          // nodes
#define NC 1024            // communities
#define NM 101024          // NN + NC
#define NE 3200000         // edges
#define DD 128             // feature dim

typedef __attribute__((ext_vector_type(8))) short s16x8;
typedef __attribute__((ext_vector_type(4))) float f32x4;

#define MFMA __builtin_amdgcn_mfma_f32_16x16x32_bf16

__device__ __forceinline__ short f2bf(float f) {
  unsigned u = __float_as_uint(f);
  u = (u + 0x7FFFu + ((u >> 16) & 1u)) >> 16;   // RNE
  return (short)u;
}
__device__ __forceinline__ float bf2f(short h) {
  return __uint_as_float(((unsigned)(unsigned short)h) << 16);
}

// ---------------- zero init (u2acc | colsum | hist contiguous) ----------------
__global__ __launch_bounds__(256) void k_zero(int* __restrict__ p, int n) {
  int t = blockIdx.x * 256 + threadIdx.x;
  if (t < n) p[t] = 0;
}

// ------------- pack W into B-fragment layout, split hi/lo bf16 -------------
// frag layout value = B[k][d]; k = ks*32 + g*8 + j, lane = g*16 + (d&15), dt = d>>4
__global__ __launch_bounds__(256) void k_wpack(const float* __restrict__ W,
                                               short* __restrict__ wh,
                                               short* __restrict__ wl) {
  int t = blockIdx.x * 256 + threadIdx.x;   // 16384
  int k = t >> 7, d = t & 127;
  float v = W[t];
  short h = f2bf(v);
  short l = f2bf(v - bf2f(h));
  int idx = (((k >> 5) * 8 + (d >> 4)) * 64 + ((k >> 3) & 3) * 16 + (d & 15)) * 8 + (k & 7);
  wh[idx] = h;
  wl[idx] = l;
}

// ------------- support = x @ W, split-bf16 (3 MFMA terms ~ fp32) -------------
__global__ __launch_bounds__(256) void k_support(const float* __restrict__ x,
                                                 const short* __restrict__ wh,
                                                 const short* __restrict__ wl,
                                                 float* __restrict__ sup) {
  int wave = threadIdx.x >> 6, lane = threadIdx.x & 63;
  int r0 = blockIdx.x * 64 + wave * 16;
  int arow = r0 + (lane & 15);
  if (arow >= NM) arow = NM - 1;
  int kb = (lane >> 4) * 8;
  f32x4 acc[8];
  #pragma unroll
  for (int dt = 0; dt < 8; ++dt)
    #pragma unroll
    for (int q = 0; q < 4; ++q) acc[dt][q] = 0.f;

  #pragma unroll
  for (int ks = 0; ks < 4; ++ks) {
    const float* ap = x + (size_t)arow * DD + ks * 32 + kb;
    float4 v0 = *(const float4*)ap;
    float4 v1 = *(const float4*)(ap + 4);
    float vv[8] = {v0.x, v0.y, v0.z, v0.w, v1.x, v1.y, v1.z, v1.w};
    s16x8 xh, xl;
    #pragma unroll
    for (int j = 0; j < 8; ++j) {
      short h = f2bf(vv[j]);
      xh[j] = h;
      xl[j] = f2bf(vv[j] - bf2f(h));
    }
    const short* bph = wh + ks * 4096 + lane * 8;
    const short* bpl = wl + ks * 4096 + lane * 8;
    #pragma unroll
    for (int dt = 0; dt < 8; ++dt) {
      s16x8 bh = *(const s16x8*)(bph + dt * 512);
      s16x8 bl = *(const s16x8*)(bpl + dt * 512);
      acc[dt] = MFMA(xh, bh, acc[dt], 0, 0, 0);
      acc[dt] = MFMA(xl, bh, acc[dt], 0, 0, 0);
      acc[dt] = MFMA(xh, bl, acc[dt], 0, 0, 0);
    }
  }
  int rg = (lane >> 4) * 4, cc = lane & 15;
  #pragma unroll
  for (int dt = 0; dt < 8; ++dt)
    #pragma unroll
    for (int q = 0; q < 4; ++q) {
      int rr = r0 + rg + q;
      if (rr < NM) sup[(size_t)rr * DD + dt * 16 + cc] = acc[dt][q];
    }
}

// ------------- pack support rows into bf16 B-fragment layout -------------
__global__ __launch_bounds__(256) void k_spack(const float* __restrict__ sup,
                                               short* __restrict__ bpk) {
  int t = blockIdx.x * 256 + threadIdx.x;   // 1,616,384
  int d = t & 127, ib = t >> 7;             // ib < 12628 (blocks of 8 rows)
  int rb = ib >> 2, g = ib & 3;
  s16x8 o;
  #pragma unroll
  for (int j = 0; j < 8; ++j) o[j] = f2bf(sup[(size_t)(ib * 8 + j) * DD + d]);
  *(s16x8*)(bpk + (size_t)((rb * 8 + (d >> 4)) * 64 + g * 16 + (d & 15)) * 8) = o;
}

// ------------- U1: comm_to_node = (A @ sup_comm) / rowsum -> out[0:NN) -------------
__global__ __launch_bounds__(256) void k_u1(const float* __restrict__ A,
                                            const short* __restrict__ bpk,
                                            float* __restrict__ out) {
  __shared__ float rsh[128];
  int wave = threadIdx.x >> 6, lane = threadIdx.x & 63;
  int r0 = blockIdx.x * 128 + wave * 32;
  int kb = (lane >> 4) * 8;
  f32x4 acc[2][8];
  #pragma unroll
  for (int m = 0; m < 2; ++m)
    #pragma unroll
    for (int dt = 0; dt < 8; ++dt)
      #pragma unroll
      for (int q = 0; q < 4; ++q) acc[m][dt][q] = 0.f;
  float rs[2] = {0.f, 0.f};
  int row[2];
  #pragma unroll
  for (int m = 0; m < 2; ++m) {
    int r = r0 + m * 16 + (lane & 15);
    row[m] = (r < NN) ? r : NN - 1;
  }
  for (int ks = 0; ks < 32; ++ks) {
    s16x8 af[2];
    #pragma unroll
    for (int m = 0; m < 2; ++m) {
      const float* ap = A + (size_t)row[m] * NC + ks * 32 + kb;
      float4 v0 = *(const float4*)ap;
      float4 v1 = *(const float4*)(ap + 4);
      rs[m] += v0.x + v0.y + v0.z + v0.w + v1.x + v1.y + v1.z + v1.w;
      af[m][0] = f2bf(v0.x); af[m][1] = f2bf(v0.y);
      af[m][2] = f2bf(v0.z); af[m][3] = f2bf(v0.w);
      af[m][4] = f2bf(v1.x); af[m][5] = f2bf(v1.y);
      af[m][6] = f2bf(v1.z); af[m][7] = f2bf(v1.w);
    }
    const short* bp = bpk + (size_t)(3125 + ks) * 4096 + lane * 8;
    #pragma unroll
    for (int dt = 0; dt < 8; ++dt) {
      s16x8 b = *(const s16x8*)(bp + dt * 512);
      acc[0][dt] = MFMA(af[0], b, acc[0][dt], 0, 0, 0);
      acc[1][dt] = MFMA(af[1], b, acc[1][dt], 0, 0, 0);
    }
  }
  #pragma unroll
  for (int m = 0; m < 2; ++m) {
    float v = rs[m];
    v += __shfl_xor(v, 16);
    v += __shfl_xor(v, 32);
    if (lane < 16) rsh[wave * 32 + m * 16 + lane] = v;
  }
  __syncthreads();
  int rg = (lane >> 4) * 4, cc = lane & 15;
  #pragma unroll
  for (int m = 0; m < 2; ++m)
    #pragma unroll
    for (int q = 0; q < 4; ++q) {
      int wr = wave * 32 + m * 16 + rg + q;
      int r = blockIdx.x * 128 + wr;
      if (r < NN) {
        float inv = 1.f / rsh[wr];
        #pragma unroll
        for (int dt = 0; dt < 8; ++dt)
          out[(size_t)r * DD + dt * 16 + cc] = acc[m][dt][q] * inv;
      }
    }
}

// ------------- U2 partial: A^T @ sup_nodes (atomic reduce) + colsum partials -------------
__global__ __launch_bounds__(256) void k_u2(const float* __restrict__ A,
                                            const short* __restrict__ bpk,
                                            float* __restrict__ u2,
                                            float* __restrict__ csum) {
  __shared__ short atile[128 * 40];   // [c_local][i] bf16, padded pitch 40
  int wave = threadIdx.x >> 6, lane = threadIdx.x & 63;
  int c0 = (blockIdx.x & 7) * 128;
  int s = blockIdx.x >> 3;            // 0..124, i-chunk of 800 rows
  int wc = wave * 32;
  f32x4 acc[2][8];
  #pragma unroll
  for (int m = 0; m < 2; ++m)
    #pragma unroll
    for (int dt = 0; dt < 8; ++dt)
      #pragma unroll
      for (int q = 0; q < 4; ++q) acc[m][dt][q] = 0.f;
  float cs[2] = {0.f, 0.f};
  int ld_i = threadIdx.x >> 5;         // 0..7
  int ld_c = (threadIdx.x & 31) * 4;   // 0..124

  for (int kk = 0; kk < 25; ++kk) {
    int i0 = s * 800 + kk * 32;
    __syncthreads();
    #pragma unroll
    for (int it = 0; it < 4; ++it) {
      int i = it * 8 + ld_i;
      float4 v = *(const float4*)(A + (size_t)(i0 + i) * NC + c0 + ld_c);
      atile[(ld_c + 0) * 40 + i] = f2bf(v.x);
      atile[(ld_c + 1) * 40 + i] = f2bf(v.y);
      atile[(ld_c + 2) * 40 + i] = f2bf(v.z);
      atile[(ld_c + 3) * 40 + i] = f2bf(v.w);
    }
    __syncthreads();
    s16x8 af[2];
    #pragma unroll
    for (int m = 0; m < 2; ++m) {
      af[m] = *(const s16x8*)(atile + (wc + m * 16 + (lane & 15)) * 40 + (lane >> 4) * 8);
      #pragma unroll
      for (int j = 0; j < 8; ++j) cs[m] += bf2f(af[m][j]);
    }
    const short* bp = bpk + (size_t)(s * 25 + kk) * 4096 + lane * 8;
    #pragma unroll
    for (int dt = 0; dt < 8; ++dt) {
      s16x8 b = *(const s16x8*)(bp + dt * 512);
      acc[0][dt] = MFMA(af[0], b, acc[0][dt], 0, 0, 0);
      acc[1][dt] = MFMA(af[1], b, acc[1][dt], 0, 0, 0);
    }
  }
  #pragma unroll
  for (int m = 0; m < 2; ++m) {
    float v = cs[m];
    v += __shfl_xor(v, 16);
    v += __shfl_xor(v, 32);
    if (lane < 16) atomicAdd(&csum[c0 + wc + m * 16 + lane], v);
  }
  int rg = (lane >> 4) * 4, cc = lane & 15;
  #pragma unroll
  for (int m = 0; m < 2; ++m)
    #pragma unroll
    for (int dt = 0; dt < 8; ++dt)
      #pragma unroll
      for (int q = 0; q < 4; ++q)
        atomicAdd(&u2[(size_t)(c0 + wc + m * 16 + rg + q) * DD + dt * 16 + cc],
                  acc[m][dt][q]);
}

// ------------- out2 = u2 / colsum -> out[NN:NM) -------------
__global__ __launch_bounds__(256) void k_out2(const float* __restrict__ u2,
                                              const float* __restrict__ csum,
                                              float* __restrict__ out) {
  int t = blockIdx.x * 256 + threadIdx.x;   // 131072
  int c = t >> 7;
  out[(size_t)(NN + c) * DD + (t & 127)] = u2[t] / csum[c];
}

// ------------- edge histogram -------------
__global__ __launch_bounds__(256) void k_hist(const int* __restrict__ er, int* __restrict__ hist) {
  int t = blockIdx.x * 256 + threadIdx.x;
  if (t < NE) atomicAdd(&hist[er[t]], 1);
}

// ------------- scans (hist -> exclusive offsets) -------------
__global__ __launch_bounds__(256) void k_scan1(const int* __restrict__ hist,
                                               int* __restrict__ excl,
                                               int* __restrict__ bsum) {
  __shared__ int sm[256];
  int t = threadIdx.x, g = blockIdx.x * 256 + t;
  int v = (g < NN) ? hist[g] : 0;
  sm[t] = v;
  __syncthreads();
  for (int off = 1; off < 256; off <<= 1) {
    int u = (t >= off) ? sm[t - off] : 0;
    __syncthreads();
    sm[t] += u;
    __syncthreads();
  }
  if (g < NN) excl[g] = sm[t] - v;
  if (t == 255) bsum[blockIdx.x] = sm[255];
}

__global__ __launch_bounds__(512) void k_scan2(const int* __restrict__ bsum,
                                               int* __restrict__ boff, int nb) {
  __shared__ int sm[512];
  int t = threadIdx.x;
  int v = (t < nb) ? bsum[t] : 0;
  sm[t] = v;
  __syncthreads();
  for (int off = 1; off < 512; off <<= 1) {
    int u = (t >= off) ? sm[t - off] : 0;
    __syncthreads();
    sm[t] += u;
    __syncthreads();
  }
  if (t < nb) boff[t] = sm[t] - v;
}

__global__ __launch_bounds__(256) void k_scan3(const int* __restrict__ excl,
                                               const int* __restrict__ boff,
                                               int* __restrict__ offs,
                                               int* __restrict__ cur) {
  int t = threadIdx.x, g = blockIdx.x * 256 + t;
  if (g < NN) {
    int o = excl[g] + boff[blockIdx.x];
    offs[g] = o;
    cur[g] = o;
  }
  if (g == 0) offs[NN] = NE;
}

// ------------- scatter edges into row-sorted (col,val) pairs -------------
__global__ __launch_bounds__(256) void k_scatter(const int* __restrict__ er,
                                                 const int* __restrict__ ec,
                                                 const float* __restrict__ ev,
                                                 int* __restrict__ cur,
                                                 int2* __restrict__ pairs) {
  int t = blockIdx.x * 256 + threadIdx.x;
  if (t < NE) {
    int r = er[t];
    int p = atomicAdd(&cur[r], 1);
    pairs[p] = make_int2(ec[t], __float_as_int(ev[t]));
  }
}

// ------------- SPMM: one wave per row, += into out (after k_u1) -------------
__global__ __launch_bounds__(256) void k_spmm(const int* __restrict__ offs,
                                              const int2* __restrict__ pairs,
                                              const float* __restrict__ sup,
                                              float* __restrict__ out) {
  int wave = threadIdx.x >> 6, lane = threadIdx.x & 63;
  int row = blockIdx.x * 4 + wave;   // grid 25000 -> rows exactly cover NN
  int beg = offs[row], end = offs[row + 1];
  float ax = 0.f, ay = 0.f;
  for (int e = beg; e < end; ++e) {
    int2 p = pairs[e];
    float2 v = *(const float2*)(sup + (size_t)p.x * DD + lane * 2);
    float val = __int_as_float(p.y);
    ax = fmaf(val, v.x, ax);
    ay = fmaf(val, v.y, ay);
  }
  float2* o = (float2*)(out + (size_t)row * DD);
  float2 c = o[lane];
  c.x += ax;
  c.y += ay;
  o[lane] = c;
}

extern "C" void kernel_launch(void* const* d_in, const int* in_sizes, int n_in,
                              void* d_out, int out_size, void* d_ws, size_t ws_size,
                              hipStream_t stream) {
  const float* x  = (const float*)d_in[0];
  const float* W  = (const float*)d_in[1];
  const float* A  = (const float*)d_in[2];
  const int*   er = (const int*)d_in[3];
  const int*   ec = (const int*)d_in[4];
  const float* ev = (const float*)d_in[5];
  float* out = (float*)d_out;

  char* ws = (char*)d_ws;
  size_t off = 0;
  auto alloc = [&](size_t bytes) -> void* {
    off = (off + 255) & ~(size_t)255;
    void* p = ws + off;
    off += bytes;
    return p;
  };
  float* sup   = (float*)alloc((size_t)NM * DD * 4);        // 51.7 MB
  short* bpk   = (short*)alloc((size_t)NM * DD * 2);        // 25.9 MB
  short* wh    = (short*)alloc(128 * 128 * 2);
  short* wl    = (short*)alloc(128 * 128 * 2);
  // zero region (contiguous): u2acc | colsum | hist
  float* u2    = (float*)alloc((size_t)NC * DD * 4);        // 131072 f
  float* csum  = (float*)alloc(NC * 4);                     // 1024 f
  int*   hist  = (int*)alloc(NN * 4);                       // 100000 i
  int*   excl  = (int*)alloc(NN * 4);
  int*   offs  = (int*)alloc((NN + 1) * 4);
  int*   cur   = (int*)alloc(NN * 4);
  int*   bsum  = (int*)alloc(512 * 4);
  int*   boff  = (int*)alloc(512 * 4);
  int2*  pairs = (int2*)alloc((size_t)NE * 8);              // 25.6 MB
  (void)ws_size; (void)in_sizes; (void)n_in; (void)out_size;

  const int ZN = NC * DD + NC + NN;   // 232096 dwords, contiguous from u2
  k_zero<<<dim3((ZN + 255) / 256), dim3(256), 0, stream>>>((int*)u2, ZN);
  k_wpack<<<dim3(64), dim3(256), 0, stream>>>(W, wh, wl);
  k_support<<<dim3(1579), dim3(256), 0, stream>>>(x, wh, wl, sup);
  k_spack<<<dim3(6314), dim3(256), 0, stream>>>(sup, bpk);
  k_hist<<<dim3(12500), dim3(256), 0, stream>>>(er, hist);
  k_scan1<<<dim3(391), dim3(256), 0, stream>>>(hist, excl, bsum);
  k_scan2<<<dim3(1), dim3(512), 0, stream>>>(bsum, boff, 391);
  k_scan3<<<dim3(391), dim3(256), 0, stream>>>(excl, boff, offs, cur);
  k_scatter<<<dim3(12500), dim3(256), 0, stream>>>(er, ec, ev, cur, pairs);
  k_u1<<<dim3(782), dim3(256), 0, stream>>>(A, bpk, out);
  k_u2<<<dim3(1000), dim3(256), 0, stream>>>(A, bpk, u2, csum);
  k_out2<<<dim3(512), dim3(256), 0, stream>>>(u2, csum, out);
  k_spmm<<<dim3(25000), dim3(256), 0, stream>>>(offs, pairs, sup, out);
}

// Round 2
// 1380.287 us; speedup vs baseline: 1.1936x; 1.1936x over previous
//
#include <hip/hip_runtime.h>
#include <hip/hip_fp16.h>

#define NN 100000          // nodes
#define NC 1024            // communities
#define NM 101024          // NN + NC
#define NE 3200000         // edges
#define DD 128             // feature dim

typedef __attribute__((ext_vector_type(8))) short s16x8;
typedef __attribute__((ext_vector_type(4))) float f32x4;

#define MFMA __builtin_amdgcn_mfma_f32_16x16x32_bf16

__device__ __forceinline__ short f2bf(float f) {
  unsigned u = __float_as_uint(f);
  u = (u + 0x7FFFu + ((u >> 16) & 1u)) >> 16;   // RNE
  return (short)u;
}
__device__ __forceinline__ float bf2f(short h) {
  return __uint_as_float(((unsigned)(unsigned short)h) << 16);
}

// ---------------- zero init (u2acc | colsum | hist contiguous) ----------------
__global__ __launch_bounds__(256) void k_zero(int* __restrict__ p, int n) {
  int t = blockIdx.x * 256 + threadIdx.x;
  if (t < n) p[t] = 0;
}

// ------------- pack W into B-fragment layout, split hi/lo bf16 -------------
__global__ __launch_bounds__(256) void k_wpack(const float* __restrict__ W,
                                               short* __restrict__ wh,
                                               short* __restrict__ wl) {
  int t = blockIdx.x * 256 + threadIdx.x;   // 16384
  int k = t >> 7, d = t & 127;
  float v = W[t];
  short h = f2bf(v);
  short l = f2bf(v - bf2f(h));
  int idx = (((k >> 5) * 8 + (d >> 4)) * 64 + ((k >> 3) & 3) * 16 + (d & 15)) * 8 + (k & 7);
  wh[idx] = h;
  wl[idx] = l;
}

// ------------- support = x @ W, split-bf16 (3 MFMA terms ~ fp32) -------------
__global__ __launch_bounds__(256) void k_support(const float* __restrict__ x,
                                                 const short* __restrict__ wh,
                                                 const short* __restrict__ wl,
                                                 float* __restrict__ sup) {
  int wave = threadIdx.x >> 6, lane = threadIdx.x & 63;
  int r0 = blockIdx.x * 64 + wave * 16;
  int arow = r0 + (lane & 15);
  if (arow >= NM) arow = NM - 1;
  int kb = (lane >> 4) * 8;
  f32x4 acc[8];
  #pragma unroll
  for (int dt = 0; dt < 8; ++dt)
    #pragma unroll
    for (int q = 0; q < 4; ++q) acc[dt][q] = 0.f;

  #pragma unroll
  for (int ks = 0; ks < 4; ++ks) {
    const float* ap = x + (size_t)arow * DD + ks * 32 + kb;
    float4 v0 = *(const float4*)ap;
    float4 v1 = *(const float4*)(ap + 4);
    float vv[8] = {v0.x, v0.y, v0.z, v0.w, v1.x, v1.y, v1.z, v1.w};
    s16x8 xh, xl;
    #pragma unroll
    for (int j = 0; j < 8; ++j) {
      short h = f2bf(vv[j]);
      xh[j] = h;
      xl[j] = f2bf(vv[j] - bf2f(h));
    }
    const short* bph = wh + ks * 4096 + lane * 8;
    const short* bpl = wl + ks * 4096 + lane * 8;
    #pragma unroll
    for (int dt = 0; dt < 8; ++dt) {
      s16x8 bh = *(const s16x8*)(bph + dt * 512);
      s16x8 bl = *(const s16x8*)(bpl + dt * 512);
      acc[dt] = MFMA(xh, bh, acc[dt], 0, 0, 0);
      acc[dt] = MFMA(xl, bh, acc[dt], 0, 0, 0);
      acc[dt] = MFMA(xh, bl, acc[dt], 0, 0, 0);
    }
  }
  int rg = (lane >> 4) * 4, cc = lane & 15;
  #pragma unroll
  for (int dt = 0; dt < 8; ++dt)
    #pragma unroll
    for (int q = 0; q < 4; ++q) {
      int rr = r0 + rg + q;
      if (rr < NM) sup[(size_t)rr * DD + dt * 16 + cc] = acc[dt][q];
    }
}

// ------------- fp16 row-major copy of sup_nodes for the SPMM gather -------------
__global__ __launch_bounds__(256) void k_suph(const float* __restrict__ sup,
                                              unsigned* __restrict__ suph) {
  int t = blockIdx.x * 256 + threadIdx.x;   // NN*64
  float2 f = *(const float2*)(sup + (size_t)t * 2);
  __half2 h = __floats2half2_rn(f.x, f.y);
  suph[t] = *(unsigned*)&h;
}

// ------------- pack support rows into bf16 B-fragment layout -------------
__global__ __launch_bounds__(256) void k_spack(const float* __restrict__ sup,
                                               short* __restrict__ bpk) {
  int t = blockIdx.x * 256 + threadIdx.x;   // 1,616,384
  int d = t & 127, ib = t >> 7;             // ib < 12628 (blocks of 8 rows)
  int rb = ib >> 2, g = ib & 3;
  s16x8 o;
  #pragma unroll
  for (int j = 0; j < 8; ++j) o[j] = f2bf(sup[(size_t)(ib * 8 + j) * DD + d]);
  *(s16x8*)(bpk + (size_t)((rb * 8 + (d >> 4)) * 64 + g * 16 + (d & 15)) * 8) = o;
}

// ------------- U1: comm_to_node = (A @ sup_comm) / rowsum -> out[0:NN) -------------
__global__ __launch_bounds__(256) void k_u1(const float* __restrict__ A,
                                            const short* __restrict__ bpk,
                                            float* __restrict__ out) {
  __shared__ float rsh[128];
  int wave = threadIdx.x >> 6, lane = threadIdx.x & 63;
  int r0 = blockIdx.x * 128 + wave * 32;
  int kb = (lane >> 4) * 8;
  f32x4 acc[2][8];
  #pragma unroll
  for (int m = 0; m < 2; ++m)
    #pragma unroll
    for (int dt = 0; dt < 8; ++dt)
      #pragma unroll
      for (int q = 0; q < 4; ++q) acc[m][dt][q] = 0.f;
  float rs[2] = {0.f, 0.f};
  int row[2];
  #pragma unroll
  for (int m = 0; m < 2; ++m) {
    int r = r0 + m * 16 + (lane & 15);
    row[m] = (r < NN) ? r : NN - 1;
  }
  for (int ks = 0; ks < 32; ++ks) {
    s16x8 af[2];
    #pragma unroll
    for (int m = 0; m < 2; ++m) {
      const float* ap = A + (size_t)row[m] * NC + ks * 32 + kb;
      float4 v0 = *(const float4*)ap;
      float4 v1 = *(const float4*)(ap + 4);
      rs[m] += v0.x + v0.y + v0.z + v0.w + v1.x + v1.y + v1.z + v1.w;
      af[m][0] = f2bf(v0.x); af[m][1] = f2bf(v0.y);
      af[m][2] = f2bf(v0.z); af[m][3] = f2bf(v0.w);
      af[m][4] = f2bf(v1.x); af[m][5] = f2bf(v1.y);
      af[m][6] = f2bf(v1.z); af[m][7] = f2bf(v1.w);
    }
    const short* bp = bpk + (size_t)(3125 + ks) * 4096 + lane * 8;
    #pragma unroll
    for (int dt = 0; dt < 8; ++dt) {
      s16x8 b = *(const s16x8*)(bp + dt * 512);
      acc[0][dt] = MFMA(af[0], b, acc[0][dt], 0, 0, 0);
      acc[1][dt] = MFMA(af[1], b, acc[1][dt], 0, 0, 0);
    }
  }
  #pragma unroll
  for (int m = 0; m < 2; ++m) {
    float v = rs[m];
    v += __shfl_xor(v, 16);
    v += __shfl_xor(v, 32);
    if (lane < 16) rsh[wave * 32 + m * 16 + lane] = v;
  }
  __syncthreads();
  int rg = (lane >> 4) * 4, cc = lane & 15;
  #pragma unroll
  for (int m = 0; m < 2; ++m)
    #pragma unroll
    for (int q = 0; q < 4; ++q) {
      int wr = wave * 32 + m * 16 + rg + q;
      int r = blockIdx.x * 128 + wr;
      if (r < NN) {
        float inv = 1.f / rsh[wr];
        #pragma unroll
        for (int dt = 0; dt < 8; ++dt)
          out[(size_t)r * DD + dt * 16 + cc] = acc[m][dt][q] * inv;
      }
    }
}

// ------------- U2 partial: A^T @ sup_nodes (atomic reduce) + colsum partials -------------
// double-buffered LDS: global->reg prefetch of tile kk+1 overlaps MFMA on tile kk
__global__ __launch_bounds__(256) void k_u2(const float* __restrict__ A,
                                            const short* __restrict__ bpk,
                                            float* __restrict__ u2,
                                            float* __restrict__ csum) {
  __shared__ short atile[2][128 * 40];   // [c_local][i] bf16, padded pitch 40
  int wave = threadIdx.x >> 6, lane = threadIdx.x & 63;
  int c0 = (blockIdx.x & 7) * 128;
  int s = blockIdx.x >> 3;            // 0..124, i-chunk of 800 rows
  int wc = wave * 32;
  f32x4 acc[2][8];
  #pragma unroll
  for (int m = 0; m < 2; ++m)
    #pragma unroll
    for (int dt = 0; dt < 8; ++dt)
      #pragma unroll
      for (int q = 0; q < 4; ++q) acc[m][dt][q] = 0.f;
  float cs[2] = {0.f, 0.f};
  int ld_i = threadIdx.x >> 5;         // 0..7
  int ld_c = (threadIdx.x & 31) * 4;   // 0..124

  float4 rv[4];
  #pragma unroll
  for (int it = 0; it < 4; ++it)
    rv[it] = *(const float4*)(A + (size_t)(s * 800 + it * 8 + ld_i) * NC + c0 + ld_c);
  #pragma unroll
  for (int it = 0; it < 4; ++it) {
    int i = it * 8 + ld_i;
    atile[0][(ld_c + 0) * 40 + i] = f2bf(rv[it].x);
    atile[0][(ld_c + 1) * 40 + i] = f2bf(rv[it].y);
    atile[0][(ld_c + 2) * 40 + i] = f2bf(rv[it].z);
    atile[0][(ld_c + 3) * 40 + i] = f2bf(rv[it].w);
  }
  __syncthreads();

  for (int kk = 0; kk < 25; ++kk) {
    int p = kk & 1;
    if (kk < 24) {
      int i0n = s * 800 + (kk + 1) * 32;
      #pragma unroll
      for (int it = 0; it < 4; ++it)
        rv[it] = *(const float4*)(A + (size_t)(i0n + it * 8 + ld_i) * NC + c0 + ld_c);
    }
    s16x8 af[2];
    #pragma unroll
    for (int m = 0; m < 2; ++m) {
      af[m] = *(const s16x8*)(&atile[p][(wc + m * 16 + (lane & 15)) * 40 + (lane >> 4) * 8]);
      #pragma unroll
      for (int j = 0; j < 8; ++j) cs[m] += bf2f(af[m][j]);
    }
    if (kk < 24) {
      #pragma unroll
      for (int it = 0; it < 4; ++it) {
        int i = it * 8 + ld_i;
        atile[p ^ 1][(ld_c + 0) * 40 + i] = f2bf(rv[it].x);
        atile[p ^ 1][(ld_c + 1) * 40 + i] = f2bf(rv[it].y);
        atile[p ^ 1][(ld_c + 2) * 40 + i] = f2bf(rv[it].z);
        atile[p ^ 1][(ld_c + 3) * 40 + i] = f2bf(rv[it].w);
      }
    }
    const short* bp = bpk + (size_t)(s * 25 + kk) * 4096 + lane * 8;
    #pragma unroll
    for (int dt = 0; dt < 8; ++dt) {
      s16x8 b = *(const s16x8*)(bp + dt * 512);
      acc[0][dt] = MFMA(af[0], b, acc[0][dt], 0, 0, 0);
      acc[1][dt] = MFMA(af[1], b, acc[1][dt], 0, 0, 0);
    }
    __syncthreads();
  }
  #pragma unroll
  for (int m = 0; m < 2; ++m) {
    float v = cs[m];
    v += __shfl_xor(v, 16);
    v += __shfl_xor(v, 32);
    if (lane < 16) atomicAdd(&csum[c0 + wc + m * 16 + lane], v);
  }
  int rg = (lane >> 4) * 4, cc = lane & 15;
  #pragma unroll
  for (int m = 0; m < 2; ++m)
    #pragma unroll
    for (int dt = 0; dt < 8; ++dt)
      #pragma unroll
      for (int q = 0; q < 4; ++q)
        atomicAdd(&u2[(size_t)(c0 + wc + m * 16 + rg + q) * DD + dt * 16 + cc],
                  acc[m][dt][q]);
}

// ------------- out2 = u2 / colsum -> out[NN:NM) -------------
__global__ __launch_bounds__(256) void k_out2(const float* __restrict__ u2,
                                              const float* __restrict__ csum,
                                              float* __restrict__ out) {
  int t = blockIdx.x * 256 + threadIdx.x;   // 131072
  int c = t >> 7;
  out[(size_t)(NN + c) * DD + (t & 127)] = u2[t] / csum[c];
}

// ------------- edge histogram -------------
__global__ __launch_bounds__(256) void k_hist(const int* __restrict__ er, int* __restrict__ hist) {
  int t = blockIdx.x * 256 + threadIdx.x;
  if (t < NE) atomicAdd(&hist[er[t]], 1);
}

// ------------- scans (hist -> exclusive offsets) -------------
__global__ __launch_bounds__(256) void k_scan1(const int* __restrict__ hist,
                                               int* __restrict__ excl,
                                               int* __restrict__ bsum) {
  __shared__ int sm[256];
  int t = threadIdx.x, g = blockIdx.x * 256 + t;
  int v = (g < NN) ? hist[g] : 0;
  sm[t] = v;
  __syncthreads();
  for (int off = 1; off < 256; off <<= 1) {
    int u = (t >= off) ? sm[t - off] : 0;
    __syncthreads();
    sm[t] += u;
    __syncthreads();
  }
  if (g < NN) excl[g] = sm[t] - v;
  if (t == 255) bsum[blockIdx.x] = sm[255];
}

__global__ __launch_bounds__(512) void k_scan2(const int* __restrict__ bsum,
                                               int* __restrict__ boff, int nb) {
  __shared__ int sm[512];
  int t = threadIdx.x;
  int v = (t < nb) ? bsum[t] : 0;
  sm[t] = v;
  __syncthreads();
  for (int off = 1; off < 512; off <<= 1) {
    int u = (t >= off) ? sm[t - off] : 0;
    __syncthreads();
    sm[t] += u;
    __syncthreads();
  }
  if (t < nb) boff[t] = sm[t] - v;
}

__global__ __launch_bounds__(256) void k_scan3(const int* __restrict__ excl,
                                               const int* __restrict__ boff,
                                               int* __restrict__ offs,
                                               int* __restrict__ cur) {
  int t = threadIdx.x, g = blockIdx.x * 256 + t;
  if (g < NN) {
    int o = excl[g] + boff[blockIdx.x];
    offs[g] = o;
    cur[g] = o;
  }
  if (g == 0) offs[NN] = NE;
}

// ------------- scatter edges into row-sorted (col,val) pairs -------------
__global__ __launch_bounds__(256) void k_scatter(const int* __restrict__ er,
                                                 const int* __restrict__ ec,
                                                 const float* __restrict__ ev,
                                                 int* __restrict__ cur,
                                                 int2* __restrict__ pairs) {
  int t = blockIdx.x * 256 + threadIdx.x;
  if (t < NE) {
    int r = er[t];
    int p = atomicAdd(&cur[r], 1);
    pairs[p] = make_int2(ec[t], __float_as_int(ev[t]));
  }
}

// ------------- SPMM: one wave per row, fp16 gather, unrolled x4 -------------
__global__ __launch_bounds__(256) void k_spmm(const int* __restrict__ offs,
                                              const int2* __restrict__ pairs,
                                              const unsigned* __restrict__ suph,
                                              float* __restrict__ out) {
  int wave = threadIdx.x >> 6, lane = threadIdx.x & 63;
  int row = blockIdx.x * 4 + wave;   // grid 25000 -> rows exactly cover NN
  int beg = offs[row], end = offs[row + 1];
  float ax = 0.f, ay = 0.f;
  int e = beg;
  for (; e + 4 <= end; e += 4) {
    int2 p0 = pairs[e], p1 = pairs[e + 1], p2 = pairs[e + 2], p3 = pairs[e + 3];
    unsigned g0 = suph[(size_t)p0.x * 64 + lane];
    unsigned g1 = suph[(size_t)p1.x * 64 + lane];
    unsigned g2 = suph[(size_t)p2.x * 64 + lane];
    unsigned g3 = suph[(size_t)p3.x * 64 + lane];
    float2 v0 = __half22float2(*(__half2*)&g0);
    float2 v1 = __half22float2(*(__half2*)&g1);
    float2 v2 = __half22float2(*(__half2*)&g2);
    float2 v3 = __half22float2(*(__half2*)&g3);
    float c0 = __int_as_float(p0.y), c1 = __int_as_float(p1.y);
    float c2 = __int_as_float(p2.y), c3 = __int_as_float(p3.y);
    ax = fmaf(c0, v0.x, ax); ay = fmaf(c0, v0.y, ay);
    ax = fmaf(c1, v1.x, ax); ay = fmaf(c1, v1.y, ay);
    ax = fmaf(c2, v2.x, ax); ay = fmaf(c2, v2.y, ay);
    ax = fmaf(c3, v3.x, ax); ay = fmaf(c3, v3.y, ay);
  }
  for (; e < end; ++e) {
    int2 p = pairs[e];
    unsigned g = suph[(size_t)p.x * 64 + lane];
    float2 v = __half22float2(*(__half2*)&g);
    float c = __int_as_float(p.y);
    ax = fmaf(c, v.x, ax);
    ay = fmaf(c, v.y, ay);
  }
  float2* o = (float2*)(out + (size_t)row * DD);
  float2 c = o[lane];
  c.x += ax;
  c.y += ay;
  o[lane] = c;
}

extern "C" void kernel_launch(void* const* d_in, const int* in_sizes, int n_in,
                              void* d_out, int out_size, void* d_ws, size_t ws_size,
                              hipStream_t stream) {
  const float* x  = (const float*)d_in[0];
  const float* W  = (const float*)d_in[1];
  const float* A  = (const float*)d_in[2];
  const int*   er = (const int*)d_in[3];
  const int*   ec = (const int*)d_in[4];
  const float* ev = (const float*)d_in[5];
  float* out = (float*)d_out;

  char* ws = (char*)d_ws;
  size_t off = 0;
  auto alloc = [&](size_t bytes) -> void* {
    off = (off + 255) & ~(size_t)255;
    void* p = ws + off;
    off += bytes;
    return p;
  };
  float*    sup   = (float*)alloc((size_t)NM * DD * 4);     // 51.7 MB
  short*    bpk   = (short*)alloc((size_t)NM * DD * 2);     // 25.9 MB
  unsigned* suphp = (unsigned*)alloc((size_t)NN * 64 * 4);  // 25.6 MB fp16 nodes
  short*    wh    = (short*)alloc(128 * 128 * 2);
  short*    wl    = (short*)alloc(128 * 128 * 2);
  // zero region (contiguous): u2acc | colsum | hist
  float* u2    = (float*)alloc((size_t)NC * DD * 4);        // 131072 f
  float* csum  = (float*)alloc(NC * 4);                     // 1024 f
  int*   hist  = (int*)alloc(NN * 4);                       // 100000 i
  int*   excl  = (int*)alloc(NN * 4);
  int*   offs  = (int*)alloc((NN + 1) * 4);
  int*   cur   = (int*)alloc(NN * 4);
  int*   bsum  = (int*)alloc(512 * 4);
  int*   boff  = (int*)alloc(512 * 4);
  int2*  pairs = (int2*)alloc((size_t)NE * 8);              // 25.6 MB
  (void)ws_size; (void)in_sizes; (void)n_in; (void)out_size;

  const int ZN = NC * DD + NC + NN;   // 232096 dwords, contiguous from u2
  k_zero<<<dim3((ZN + 255) / 256), dim3(256), 0, stream>>>((int*)u2, ZN);
  k_wpack<<<dim3(64), dim3(256), 0, stream>>>(W, wh, wl);
  k_support<<<dim3(1579), dim3(256), 0, stream>>>(x, wh, wl, sup);
  k_suph<<<dim3(25000), dim3(256), 0, stream>>>(sup, suphp);
  k_spack<<<dim3(6314), dim3(256), 0, stream>>>(sup, bpk);
  k_hist<<<dim3(12500), dim3(256), 0, stream>>>(er, hist);
  k_scan1<<<dim3(391), dim3(256), 0, stream>>>(hist, excl, bsum);
  k_scan2<<<dim3(1), dim3(512), 0, stream>>>(bsum, boff, 391);
  k_scan3<<<dim3(391), dim3(256), 0, stream>>>(excl, boff, offs, cur);
  k_scatter<<<dim3(12500), dim3(256), 0, stream>>>(er, ec, ev, cur, pairs);
  k_u1<<<dim3(782), dim3(256), 0, stream>>>(A, bpk, out);
  k_u2<<<dim3(1000), dim3(256), 0, stream>>>(A, bpk, u2, csum);
  k_out2<<<dim3(512), dim3(256), 0, stream>>>(u2, csum, out);
  k_spmm<<<dim3(25000), dim3(256), 0, stream>>>(offs, pairs, suphp, out);
}